// Round 7
// baseline (4230.248 us; speedup 1.0000x reference)
//
#include <hip/hip_runtime.h>
#include <math.h>

#define PI_F 3.14159265358979323846f

static __device__ __forceinline__ float2 cmulf2(float2 a, float2 b) {
    return make_float2(a.x * b.x - a.y * b.y, a.x * b.y + a.y * b.x);
}

// ---------------------------------------------------------------------------
// K1: C = A @ W^T + bias. A:[16384,512], W:[512,512] row-major.
// Tile 64x128x16 (M x N x K), 256 threads, 4x8 micro-tile per thread.
// Double-buffered LDS, 3 staged float4/thread, 1 barrier per k-tile.
// Grid (4, 256) = 1024 blocks = 4 blocks/CU -> barrier drain hidden by
// co-resident blocks. __launch_bounds__(256,4) caps VGPR at 128.
// ---------------------------------------------------------------------------
__global__ __launch_bounds__(256, 4) void gemm_nt_bias(
    const float* __restrict__ A,
    const float* __restrict__ W,
    const float* __restrict__ bias,
    float* __restrict__ C)
{
    __shared__ float As[2][16][68];    // [buf][k][m] 64 + pad
    __shared__ float Bs[2][16][132];   // [buf][k][n] 128 + pad

    const int tid = threadIdx.x;
    const int m0 = blockIdx.y * 64;
    const int n0 = blockIdx.x * 128;
    const int tx = tid & 15;        // 16 col-groups -> cols tx*4 and 64+tx*4
    const int ty = tid >> 4;        // 16 row-groups -> rows ty*4..ty*4+3
    const int lr = tid >> 2;        // 0..63 staging row
    const int lc = (tid & 3) << 2;  // 0,4,8,12 staging k-col

    const float* pa  = A + (size_t)(m0 + lr) * 512 + lc;
    const float* pw0 = W + (size_t)(n0 + lr) * 512 + lc;
    const float* pw1 = W + (size_t)(n0 + lr + 64) * 512 + lc;

    float4 ar  = *reinterpret_cast<const float4*>(pa);
    float4 w0r = *reinterpret_cast<const float4*>(pw0);
    float4 w1r = *reinterpret_cast<const float4*>(pw1);

    As[0][lc + 0][lr] = ar.x;  As[0][lc + 1][lr] = ar.y;
    As[0][lc + 2][lr] = ar.z;  As[0][lc + 3][lr] = ar.w;
    Bs[0][lc + 0][lr] = w0r.x; Bs[0][lc + 1][lr] = w0r.y;
    Bs[0][lc + 2][lr] = w0r.z; Bs[0][lc + 3][lr] = w0r.w;
    Bs[0][lc + 0][lr + 64] = w1r.x; Bs[0][lc + 1][lr + 64] = w1r.y;
    Bs[0][lc + 2][lr + 64] = w1r.z; Bs[0][lc + 3][lr + 64] = w1r.w;
    __syncthreads();

    float acc[4][8];
#pragma unroll
    for (int i = 0; i < 4; ++i)
#pragma unroll
        for (int j = 0; j < 8; ++j) acc[i][j] = 0.f;

    int cur = 0;
#pragma unroll 1
    for (int kt = 0; kt < 32; ++kt) {
        if (kt < 31) {
            const int kn = (kt + 1) << 4;
            ar  = *reinterpret_cast<const float4*>(pa + kn);
            w0r = *reinterpret_cast<const float4*>(pw0 + kn);
            w1r = *reinterpret_cast<const float4*>(pw1 + kn);
        }
#pragma unroll
        for (int kk = 0; kk < 16; ++kk) {
            const float4 f0 = *reinterpret_cast<const float4*>(&As[cur][kk][ty << 2]);
            const float4 g0 = *reinterpret_cast<const float4*>(&Bs[cur][kk][tx << 2]);
            const float4 g1 = *reinterpret_cast<const float4*>(&Bs[cur][kk][64 + (tx << 2)]);
            const float a[4] = {f0.x, f0.y, f0.z, f0.w};
            const float b[8] = {g0.x, g0.y, g0.z, g0.w, g1.x, g1.y, g1.z, g1.w};
#pragma unroll
            for (int i = 0; i < 4; ++i)
#pragma unroll
                for (int j = 0; j < 8; ++j)
                    acc[i][j] = fmaf(a[i], b[j], acc[i][j]);
        }
        if (kt < 31) {
            const int nb = cur ^ 1;
            As[nb][lc + 0][lr] = ar.x;  As[nb][lc + 1][lr] = ar.y;
            As[nb][lc + 2][lr] = ar.z;  As[nb][lc + 3][lr] = ar.w;
            Bs[nb][lc + 0][lr] = w0r.x; Bs[nb][lc + 1][lr] = w0r.y;
            Bs[nb][lc + 2][lr] = w0r.z; Bs[nb][lc + 3][lr] = w0r.w;
            Bs[nb][lc + 0][lr + 64] = w1r.x; Bs[nb][lc + 1][lr + 64] = w1r.y;
            Bs[nb][lc + 2][lr + 64] = w1r.z; Bs[nb][lc + 3][lr + 64] = w1r.w;
            __syncthreads();
            cur = nb;
        }
    }

    const float4 bv0 = *reinterpret_cast<const float4*>(bias + n0 + (tx << 2));
    const float4 bv1 = *reinterpret_cast<const float4*>(bias + n0 + 64 + (tx << 2));
#pragma unroll
    for (int i = 0; i < 4; ++i) {
        const int r = m0 + (ty << 2) + i;
        float4 o0, o1;
        o0.x = acc[i][0] + bv0.x; o0.y = acc[i][1] + bv0.y;
        o0.z = acc[i][2] + bv0.z; o0.w = acc[i][3] + bv0.w;
        o1.x = acc[i][4] + bv1.x; o1.y = acc[i][5] + bv1.y;
        o1.z = acc[i][6] + bv1.z; o1.w = acc[i][7] + bv1.w;
        *reinterpret_cast<float4*>(C + (size_t)r * 512 + n0 + (tx << 2)) = o0;
        *reinterpret_cast<float4*>(C + (size_t)r * 512 + n0 + 64 + (tx << 2)) = o1;
    }
}

// ---------------------------------------------------------------------------
// K2: rfft-512 along L + top-4 mask. Packed-real trick: 16 real columns ->
// 8 complex FFT-512, radix-8-grouped DIF (3 LDS round trips), unpack via
// conjugate symmetry, per-real-column top-4 |.|^2 threshold, masked write.
// dst layout: [b][f][d] float2.
// ---------------------------------------------------------------------------
__global__ __launch_bounds__(256) void fft_topk_mask(
    const float* __restrict__ src,   // [B][512][512]
    float* __restrict__ dst)         // [B][257][512] float2
{
    const int b  = blockIdx.x >> 5;
    const int dt = blockIdx.x & 31;
    const int tid = threadIdx.x;

    __shared__ float2 Zs[8][522];    // 8 complex columns, padded stride
    __shared__ float2 TW[256];       // TW[j] = exp(-2*pi*i*j/512)
    __shared__ float4 red4[16][16];
    __shared__ float  thr2[16];

    {
        float sn, cs;
        sincosf(-PI_F * (float)tid * (1.0f / 256.0f), &sn, &cs);
        TW[tid] = make_float2(cs, sn);
    }

    // load: Zs[c][l] = (x_{2c}[l], x_{2c+1}[l])
    {
        const int c  = tid & 7;
        const int l0 = tid >> 3;     // 0..31
        const float* p = src + (size_t)b * 262144 + dt * 16 + 2 * c;
#pragma unroll
        for (int it = 0; it < 16; ++it) {
            const int l = l0 + (it << 5);
            Zs[c][l] = *reinterpret_cast<const float2*>(p + (size_t)l * 512);
        }
    }
    __syncthreads();

#define BF(aa, bb, tt) { \
        const float2 s_ = make_float2(aa.x + bb.x, aa.y + bb.y); \
        const float2 d_ = make_float2(aa.x - bb.x, aa.y - bb.y); \
        aa = s_; bb = cmulf2(d_, tt); }

    // 3 grouped DIF stage-triples: s = 0, 3, 6
    {
        const int c  = tid & 7;
        const int g0 = tid >> 3;     // 0..31 ; handles g0 and g0+32
#pragma unroll
        for (int grp = 0; grp < 3; ++grp) {
            const int s  = grp * 3;
            const int lg = 6 - s;            // log2(sigma): 6,3,0
            const int bs = 512 >> s;         // block size: 512,64,8
#pragma unroll
            for (int h = 0; h < 2; ++h) {
                const int g   = g0 + (h << 5);
                const int j   = g & ((1 << lg) - 1);
                const int blk = g >> lg;
                const int base = blk * bs + j;
                const int J   = j << s;      // < 64

                float2 x0 = Zs[c][base];
                float2 x1 = Zs[c][base + (1 << lg)];
                float2 x2 = Zs[c][base + (2 << lg)];
                float2 x3 = Zs[c][base + (3 << lg)];
                float2 x4 = Zs[c][base + (4 << lg)];
                float2 x5 = Zs[c][base + (5 << lg)];
                float2 x6 = Zs[c][base + (6 << lg)];
                float2 x7 = Zs[c][base + (7 << lg)];

                const float2 tA0 = TW[J];
                const float2 tA1 = TW[J + 64];
                const float2 tA2 = TW[J + 128];
                const float2 tA3 = TW[J + 192];
                BF(x0, x4, tA0); BF(x1, x5, tA1);
                BF(x2, x6, tA2); BF(x3, x7, tA3);

                const float2 tB0 = TW[2 * J];
                const float2 tB1 = TW[2 * J + 128];
                BF(x0, x2, tB0); BF(x1, x3, tB1);
                BF(x4, x6, tB0); BF(x5, x7, tB1);

                const float2 tC = TW[4 * J];
                BF(x0, x1, tC); BF(x2, x3, tC);
                BF(x4, x5, tC); BF(x6, x7, tC);

                Zs[c][base]             = x0;
                Zs[c][base + (1 << lg)] = x1;
                Zs[c][base + (2 << lg)] = x2;
                Zs[c][base + (3 << lg)] = x3;
                Zs[c][base + (4 << lg)] = x4;
                Zs[c][base + (5 << lg)] = x5;
                Zs[c][base + (6 << lg)] = x6;
                Zs[c][base + (7 << lg)] = x7;
            }
            __syncthreads();
        }
    }
#undef BF

    // FFT result: FFT[k] = Zs[c][rev9(k)].  Unpack + top-4 threshold.
    {
        const int rc = tid & 15;          // real column 0..15
        const int fi = tid >> 4;          // 0..15
        const int cc = rc >> 1;
        const int part = rc & 1;
        float t0 = -1.f, t1 = -1.f, t2 = -1.f, t3 = -1.f;
        for (int f = fi; f <= 256; f += 16) {
            const int i1 = (int)(__brev((unsigned)f) >> 23);
            const int i2 = (int)(__brev((unsigned)((512 - f) & 511)) >> 23);
            const float2 z1 = Zs[cc][i1];
            const float2 z2 = Zs[cc][i2];
            float re, im;
            if (part == 0) { re = 0.5f * (z1.x + z2.x); im = 0.5f * (z1.y - z2.y); }
            else           { re = 0.5f * (z1.y + z2.y); im = 0.5f * (z2.x - z1.x); }
            const float a = re * re + im * im;
            if (a > t3) {
                if (a > t0)      { t3 = t2; t2 = t1; t1 = t0; t0 = a; }
                else if (a > t1) { t3 = t2; t2 = t1; t1 = a; }
                else if (a > t2) { t3 = t2; t2 = a; }
                else               t3 = a;
            }
        }
        red4[rc][fi] = make_float4(t0, t1, t2, t3);
        __syncthreads();
        if (tid < 16) {
            float m0 = -1.f, m1 = -1.f, m2 = -1.f, m3 = -1.f;
            for (int q2 = 0; q2 < 16; ++q2) {
                const float4 c4 = red4[tid][q2];
                const float vals[4] = {c4.x, c4.y, c4.z, c4.w};
#pragma unroll
                for (int q = 0; q < 4; ++q) {
                    const float a = vals[q];
                    if (a > m3) {
                        if (a > m0)      { m3 = m2; m2 = m1; m1 = m0; m0 = a; }
                        else if (a > m1) { m3 = m2; m2 = m1; m1 = a; }
                        else if (a > m2) { m3 = m2; m2 = a; }
                        else               m3 = a;
                    }
                }
            }
            thr2[tid] = m3;
        }
        __syncthreads();

        // masked write (recompute unpack identically)
        const float th = thr2[rc];
        float* outp = dst + ((size_t)b * (257 * 512) + (size_t)dt * 16 + rc) * 2;
        for (int f = fi; f <= 256; f += 16) {
            const int i1 = (int)(__brev((unsigned)f) >> 23);
            const int i2 = (int)(__brev((unsigned)((512 - f) & 511)) >> 23);
            const float2 z1 = Zs[cc][i1];
            const float2 z2 = Zs[cc][i2];
            float re, im;
            if (part == 0) { re = 0.5f * (z1.x + z2.x); im = 0.5f * (z1.y - z2.y); }
            else           { re = 0.5f * (z1.y + z2.y); im = 0.5f * (z2.x - z1.x); }
            const float a = re * re + im * im;
            const float2 o = (a >= th) ? make_float2(re, im) : make_float2(0.f, 0.f);
            *reinterpret_cast<float2*>(outp + (size_t)f * 1024) = o;
        }
    }
}

// ---------------------------------------------------------------------------
// K3: per (b,f) row over d=512: att = qf*conj(kf); dual softmax; ctx = sm*vf.
// ---------------------------------------------------------------------------
__global__ __launch_bounds__(256) void att_softmax_ctx(
    const float* __restrict__ qf,
    const float* __restrict__ kf,
    float* __restrict__ vf)
{
    const int blk = blockIdx.x;
    const int b = blk / 257;
    const int f = blk % 257;
    const size_t row = ((size_t)b * 257 + f) * 512 * 2;
    const int tid = threadIdx.x;

    __shared__ float sred[20];

    const float4 q2 = *reinterpret_cast<const float4*>(qf + row + tid * 4);
    const float4 k2 = *reinterpret_cast<const float4*>(kf + row + tid * 4);
    const float4 v2 = *reinterpret_cast<const float4*>(vf + row + tid * 4);

    const float re0 = q2.x * k2.x + q2.y * k2.y;
    const float im0 = q2.y * k2.x - q2.x * k2.y;
    const float re1 = q2.z * k2.z + q2.w * k2.w;
    const float im1 = q2.w * k2.z - q2.z * k2.w;

    float mr = fmaxf(re0, re1), mi = fmaxf(im0, im1);
#pragma unroll
    for (int o = 32; o; o >>= 1) {
        mr = fmaxf(mr, __shfl_down(mr, o, 64));
        mi = fmaxf(mi, __shfl_down(mi, o, 64));
    }
    const int wid = tid >> 6, lane = tid & 63;
    if (lane == 0) { sred[wid] = mr; sred[4 + wid] = mi; }
    __syncthreads();
    if (tid == 0) {
        sred[16] = fmaxf(fmaxf(sred[0], sred[1]), fmaxf(sred[2], sred[3]));
        sred[17] = fmaxf(fmaxf(sred[4], sred[5]), fmaxf(sred[6], sred[7]));
    }
    __syncthreads();
    const float Mr = sred[16], Mi = sred[17];

    const float er0 = expf(re0 - Mr), er1 = expf(re1 - Mr);
    const float ei0 = expf(im0 - Mi), ei1 = expf(im1 - Mi);
    float sr = er0 + er1, si = ei0 + ei1;
#pragma unroll
    for (int o = 32; o; o >>= 1) {
        sr += __shfl_down(sr, o, 64);
        si += __shfl_down(si, o, 64);
    }
    if (lane == 0) { sred[8 + wid] = sr; sred[12 + wid] = si; }
    __syncthreads();
    if (tid == 0) {
        sred[18] = (sred[8] + sred[9]) + (sred[10] + sred[11]);
        sred[19] = (sred[12] + sred[13]) + (sred[14] + sred[15]);
    }
    __syncthreads();
    const float iSr = 1.0f / sred[18];
    const float iSi = 1.0f / sred[19];

    const float ar0 = er0 * iSr, ai0 = ei0 * iSi;
    const float ar1 = er1 * iSr, ai1 = ei1 * iSi;
    float4 o;
    o.x = ar0 * v2.x - ai0 * v2.y;
    o.y = ar0 * v2.y + ai0 * v2.x;
    o.z = ar1 * v2.z - ai1 * v2.w;
    o.w = ar1 * v2.w + ai1 * v2.z;
    *reinterpret_cast<float4*>(vf + row + tid * 4) = o;
}

// ---------------------------------------------------------------------------
// K4: sparse inverse rDFT along f per (b,d) column + residual add.
// ---------------------------------------------------------------------------
__global__ __launch_bounds__(256) void irfft_residual(
    const float* __restrict__ ctx,    // [B][257][512] float2
    const float* __restrict__ query,  // [B][512][512]
    float* __restrict__ x)            // [B][512][512]
{
    const int b  = blockIdx.x >> 5;
    const int dt = blockIdx.x & 31;
    const int tid = threadIdx.x;

    __shared__ float2 Cs[16][259];
    __shared__ float2 Tt[512];        // (cos, sin)(2*pi*j/512)

    for (int j = tid; j < 512; j += 256) {
        float sn, cs;
        sincosf(PI_F * (float)j * (1.0f / 256.0f), &sn, &cs);
        Tt[j] = make_float2(cs, sn);
    }
    {
        const int col = tid & 15;
        const int fr  = tid >> 4;
        const float* src = ctx + ((size_t)b * (257 * 512) + (size_t)dt * 16) * 2;
        for (int f = fr; f <= 256; f += 16) {
            Cs[col][f] = *reinterpret_cast<const float2*>(src + ((size_t)f * 512 + col) * 2);
        }
    }
    __syncthreads();

    const int col = tid & 15;
    const int w   = tid >> 4;
    float acc[32];
#pragma unroll
    for (int i = 0; i < 32; ++i) acc[i] = 0.f;

    for (int f = 0; f <= 256; ++f) {
        const float2 cv = Cs[col][f];
        if (cv.x != 0.f || cv.y != 0.f) {
            const float wgt = (f == 0 || f == 256) ? 1.f : 2.f;
            const float cr = cv.x * wgt, ci = cv.y * wgt;
            int idx = (f * w) & 511;
            const int stp = (f << 4) & 511;
#pragma unroll
            for (int i = 0; i < 32; ++i) {
                const float2 tw = Tt[idx];
                acc[i] = fmaf(cr, tw.x, fmaf(-ci, tw.y, acc[i]));
                idx = (idx + stp) & 511;
            }
        }
    }

    const float* qcol = query + (size_t)b * (512 * 512) + dt * 16 + col;
    float* xcol = x + (size_t)b * (512 * 512) + dt * 16 + col;
#pragma unroll
    for (int i = 0; i < 32; ++i) {
        const int l = w + (i << 4);
        xcol[(size_t)l * 512] = acc[i] * (1.0f / 512.0f) + qcol[(size_t)l * 512];
    }
}

// ---------------------------------------------------------------------------
// K5: LayerNorm along d.
// ---------------------------------------------------------------------------
__global__ __launch_bounds__(256) void layernorm_out(
    const float* __restrict__ x,
    const float* __restrict__ gamma,
    const float* __restrict__ beta,
    float* __restrict__ out)
{
    const int row = blockIdx.x;
    const float* xr = x + (size_t)row * 512;
    const int tid = threadIdx.x;
    __shared__ float sred[10];

    const float2 v = *reinterpret_cast<const float2*>(xr + tid * 2);
    float s = v.x + v.y;
    float q = v.x * v.x + v.y * v.y;
#pragma unroll
    for (int o = 32; o; o >>= 1) {
        s += __shfl_down(s, o, 64);
        q += __shfl_down(q, o, 64);
    }
    const int wid = tid >> 6, lane = tid & 63;
    if (lane == 0) { sred[wid] = s; sred[4 + wid] = q; }
    __syncthreads();
    if (tid == 0) {
        sred[8] = (sred[0] + sred[1]) + (sred[2] + sred[3]);
        sred[9] = (sred[4] + sred[5]) + (sred[6] + sred[7]);
    }
    __syncthreads();
    const float mean = sred[8] * (1.0f / 512.0f);
    const float var  = sred[9] * (1.0f / 512.0f) - mean * mean;
    const float rstd = 1.0f / sqrtf(var + 1e-5f);
    const float2 g  = *reinterpret_cast<const float2*>(gamma + tid * 2);
    const float2 be = *reinterpret_cast<const float2*>(beta + tid * 2);
    float2 o;
    o.x = (v.x - mean) * rstd * g.x + be.x;
    o.y = (v.y - mean) * rstd * g.y + be.y;
    *reinterpret_cast<float2*>(out + (size_t)row * 512 + tid * 2) = o;
}

// ---------------------------------------------------------------------------
extern "C" void kernel_launch(void* const* d_in, const int* in_sizes, int n_in,
                              void* d_out, int out_size, void* d_ws, size_t ws_size,
                              hipStream_t stream)
{
    const float* key   = (const float*)d_in[0];
    const float* value = (const float*)d_in[1];
    const float* query = (const float*)d_in[2];
    const float* Wk    = (const float*)d_in[3];
    const float* bk    = (const float*)d_in[4];
    const float* Wv    = (const float*)d_in[5];
    const float* bv    = (const float*)d_in[6];
    const float* Wq    = (const float*)d_in[7];
    const float* bq    = (const float*)d_in[8];
    const float* gamma = (const float*)d_in[9];
    const float* beta  = (const float*)d_in[10];
    float* out = (float*)d_out;

    float* ws = (float*)d_ws;
    float* tdom = ws;
    float* freq = ws + 8388608;
    const size_t FQ = 8421376;   // 32*257*512*2

    const float* Xs[3] = {key, value, query};
    const float* Wm[3] = {Wk, Wv, Wq};
    const float* Bs[3] = {bk, bv, bq};
    for (int t = 0; t < 3; ++t) {
        gemm_nt_bias<<<dim3(4, 256), 256, 0, stream>>>(Xs[t], Wm[t], Bs[t], tdom);
        fft_topk_mask<<<1024, 256, 0, stream>>>(tdom, freq + (size_t)t * FQ);
    }
    float* kfp = freq;
    float* vfp = freq + FQ;
    float* qfp = freq + 2 * FQ;

    att_softmax_ctx<<<32 * 257, 256, 0, stream>>>(qfp, kfp, vfp);
    irfft_residual<<<1024, 256, 0, stream>>>(vfp, query, tdom);
    layernorm_out<<<16384, 256, 0, stream>>>(tdom, gamma, beta, out);
}

// Round 9
// 838.544 us; speedup vs baseline: 5.0448x; 5.0448x over previous
//
#include <hip/hip_runtime.h>
#include <math.h>

#define PI_F 3.14159265358979323846f

static __device__ __forceinline__ float2 cmulf2(float2 a, float2 b) {
    return make_float2(a.x * b.x - a.y * b.y, a.x * b.y + a.y * b.x);
}

// ---------------------------------------------------------------------------
// K1: C = A @ W^T + bias. A:[16384,512], W:[512,512] row-major.
// Tile 64x128x16 (M x N x K), 256 threads, 4x8 micro-tile per thread.
// Double-buffered LDS, 3 staged float4/thread, 1 barrier per k-tile.
// Grid (4, 256) = 1024 blocks = 4 blocks/CU.
// NOTE: no min-occupancy arg in __launch_bounds__ — capping VGPR to 64
// spilled the accumulators to scratch (6.6 GB traffic, 1330 us; round 7).
// ---------------------------------------------------------------------------
__global__ __launch_bounds__(256) void gemm_nt_bias(
    const float* __restrict__ A,
    const float* __restrict__ W,
    const float* __restrict__ bias,
    float* __restrict__ C)
{
    __shared__ float As[2][16][68];    // [buf][k][m] 64 + pad
    __shared__ float Bs[2][16][132];   // [buf][k][n] 128 + pad

    const int tid = threadIdx.x;
    const int m0 = blockIdx.y * 64;
    const int n0 = blockIdx.x * 128;
    const int tx = tid & 15;        // 16 col-groups -> cols tx*4 and 64+tx*4
    const int ty = tid >> 4;        // 16 row-groups -> rows ty*4..ty*4+3
    const int lr = tid >> 2;        // 0..63 staging row
    const int lc = (tid & 3) << 2;  // 0,4,8,12 staging k-col

    const float* pa  = A + (size_t)(m0 + lr) * 512 + lc;
    const float* pw0 = W + (size_t)(n0 + lr) * 512 + lc;
    const float* pw1 = W + (size_t)(n0 + lr + 64) * 512 + lc;

    float4 ar  = *reinterpret_cast<const float4*>(pa);
    float4 w0r = *reinterpret_cast<const float4*>(pw0);
    float4 w1r = *reinterpret_cast<const float4*>(pw1);

    As[0][lc + 0][lr] = ar.x;  As[0][lc + 1][lr] = ar.y;
    As[0][lc + 2][lr] = ar.z;  As[0][lc + 3][lr] = ar.w;
    Bs[0][lc + 0][lr] = w0r.x; Bs[0][lc + 1][lr] = w0r.y;
    Bs[0][lc + 2][lr] = w0r.z; Bs[0][lc + 3][lr] = w0r.w;
    Bs[0][lc + 0][lr + 64] = w1r.x; Bs[0][lc + 1][lr + 64] = w1r.y;
    Bs[0][lc + 2][lr + 64] = w1r.z; Bs[0][lc + 3][lr + 64] = w1r.w;
    __syncthreads();

    float acc[4][8];
#pragma unroll
    for (int i = 0; i < 4; ++i)
#pragma unroll
        for (int j = 0; j < 8; ++j) acc[i][j] = 0.f;

    int cur = 0;
#pragma unroll 1
    for (int kt = 0; kt < 32; ++kt) {
        if (kt < 31) {
            const int kn = (kt + 1) << 4;
            ar  = *reinterpret_cast<const float4*>(pa + kn);
            w0r = *reinterpret_cast<const float4*>(pw0 + kn);
            w1r = *reinterpret_cast<const float4*>(pw1 + kn);
        }
#pragma unroll
        for (int kk = 0; kk < 16; ++kk) {
            const float4 f0 = *reinterpret_cast<const float4*>(&As[cur][kk][ty << 2]);
            const float4 g0 = *reinterpret_cast<const float4*>(&Bs[cur][kk][tx << 2]);
            const float4 g1 = *reinterpret_cast<const float4*>(&Bs[cur][kk][64 + (tx << 2)]);
            const float a[4] = {f0.x, f0.y, f0.z, f0.w};
            const float b[8] = {g0.x, g0.y, g0.z, g0.w, g1.x, g1.y, g1.z, g1.w};
#pragma unroll
            for (int i = 0; i < 4; ++i)
#pragma unroll
                for (int j = 0; j < 8; ++j)
                    acc[i][j] = fmaf(a[i], b[j], acc[i][j]);
        }
        if (kt < 31) {
            const int nb = cur ^ 1;
            As[nb][lc + 0][lr] = ar.x;  As[nb][lc + 1][lr] = ar.y;
            As[nb][lc + 2][lr] = ar.z;  As[nb][lc + 3][lr] = ar.w;
            Bs[nb][lc + 0][lr] = w0r.x; Bs[nb][lc + 1][lr] = w0r.y;
            Bs[nb][lc + 2][lr] = w0r.z; Bs[nb][lc + 3][lr] = w0r.w;
            Bs[nb][lc + 0][lr + 64] = w1r.x; Bs[nb][lc + 1][lr + 64] = w1r.y;
            Bs[nb][lc + 2][lr + 64] = w1r.z; Bs[nb][lc + 3][lr + 64] = w1r.w;
            __syncthreads();
            cur = nb;
        }
    }

    const float4 bv0 = *reinterpret_cast<const float4*>(bias + n0 + (tx << 2));
    const float4 bv1 = *reinterpret_cast<const float4*>(bias + n0 + 64 + (tx << 2));
#pragma unroll
    for (int i = 0; i < 4; ++i) {
        const int r = m0 + (ty << 2) + i;
        float4 o0, o1;
        o0.x = acc[i][0] + bv0.x; o0.y = acc[i][1] + bv0.y;
        o0.z = acc[i][2] + bv0.z; o0.w = acc[i][3] + bv0.w;
        o1.x = acc[i][4] + bv1.x; o1.y = acc[i][5] + bv1.y;
        o1.z = acc[i][6] + bv1.z; o1.w = acc[i][7] + bv1.w;
        *reinterpret_cast<float4*>(C + (size_t)r * 512 + n0 + (tx << 2)) = o0;
        *reinterpret_cast<float4*>(C + (size_t)r * 512 + n0 + 64 + (tx << 2)) = o1;
    }
}

// ---------------------------------------------------------------------------
// K2: rfft-512 along L + top-4 mask. Packed-real trick: 16 real columns ->
// 8 complex FFT-512, radix-8-grouped DIF (3 LDS round trips), unpack via
// conjugate symmetry, per-real-column top-4 |.|^2 threshold, masked write.
// dst layout: [b][f][d] float2.
// ---------------------------------------------------------------------------
__global__ __launch_bounds__(256) void fft_topk_mask(
    const float* __restrict__ src,   // [B][512][512]
    float* __restrict__ dst)         // [B][257][512] float2
{
    const int b  = blockIdx.x >> 5;
    const int dt = blockIdx.x & 31;
    const int tid = threadIdx.x;

    __shared__ float2 Zs[8][522];    // 8 complex columns, padded stride
    __shared__ float2 TW[256];       // TW[j] = exp(-2*pi*i*j/512)
    __shared__ float4 red4[16][16];
    __shared__ float  thr2[16];

    {
        float sn, cs;
        sincosf(-PI_F * (float)tid * (1.0f / 256.0f), &sn, &cs);
        TW[tid] = make_float2(cs, sn);
    }

    // load: Zs[c][l] = (x_{2c}[l], x_{2c+1}[l])
    {
        const int c  = tid & 7;
        const int l0 = tid >> 3;     // 0..31
        const float* p = src + (size_t)b * 262144 + dt * 16 + 2 * c;
#pragma unroll
        for (int it = 0; it < 16; ++it) {
            const int l = l0 + (it << 5);
            Zs[c][l] = *reinterpret_cast<const float2*>(p + (size_t)l * 512);
        }
    }
    __syncthreads();

#define BF(aa, bb, tt) { \
        const float2 s_ = make_float2(aa.x + bb.x, aa.y + bb.y); \
        const float2 d_ = make_float2(aa.x - bb.x, aa.y - bb.y); \
        aa = s_; bb = cmulf2(d_, tt); }

    // 3 grouped DIF stage-triples: s = 0, 3, 6
    {
        const int c  = tid & 7;
        const int g0 = tid >> 3;     // 0..31 ; handles g0 and g0+32
#pragma unroll
        for (int grp = 0; grp < 3; ++grp) {
            const int s  = grp * 3;
            const int lg = 6 - s;            // log2(sigma): 6,3,0
            const int bs = 512 >> s;         // block size: 512,64,8
#pragma unroll
            for (int h = 0; h < 2; ++h) {
                const int g   = g0 + (h << 5);
                const int j   = g & ((1 << lg) - 1);
                const int blk = g >> lg;
                const int base = blk * bs + j;
                const int J   = j << s;      // < 64

                float2 x0 = Zs[c][base];
                float2 x1 = Zs[c][base + (1 << lg)];
                float2 x2 = Zs[c][base + (2 << lg)];
                float2 x3 = Zs[c][base + (3 << lg)];
                float2 x4 = Zs[c][base + (4 << lg)];
                float2 x5 = Zs[c][base + (5 << lg)];
                float2 x6 = Zs[c][base + (6 << lg)];
                float2 x7 = Zs[c][base + (7 << lg)];

                const float2 tA0 = TW[J];
                const float2 tA1 = TW[J + 64];
                const float2 tA2 = TW[J + 128];
                const float2 tA3 = TW[J + 192];
                BF(x0, x4, tA0); BF(x1, x5, tA1);
                BF(x2, x6, tA2); BF(x3, x7, tA3);

                const float2 tB0 = TW[2 * J];
                const float2 tB1 = TW[2 * J + 128];
                BF(x0, x2, tB0); BF(x1, x3, tB1);
                BF(x4, x6, tB0); BF(x5, x7, tB1);

                const float2 tC = TW[4 * J];
                BF(x0, x1, tC); BF(x2, x3, tC);
                BF(x4, x5, tC); BF(x6, x7, tC);

                Zs[c][base]             = x0;
                Zs[c][base + (1 << lg)] = x1;
                Zs[c][base + (2 << lg)] = x2;
                Zs[c][base + (3 << lg)] = x3;
                Zs[c][base + (4 << lg)] = x4;
                Zs[c][base + (5 << lg)] = x5;
                Zs[c][base + (6 << lg)] = x6;
                Zs[c][base + (7 << lg)] = x7;
            }
            __syncthreads();
        }
    }
#undef BF

    // FFT result: FFT[k] = Zs[c][rev9(k)].  Unpack + top-4 threshold.
    {
        const int rc = tid & 15;          // real column 0..15
        const int fi = tid >> 4;          // 0..15
        const int cc = rc >> 1;
        const int part = rc & 1;
        float t0 = -1.f, t1 = -1.f, t2 = -1.f, t3 = -1.f;
        for (int f = fi; f <= 256; f += 16) {
            const int i1 = (int)(__brev((unsigned)f) >> 23);
            const int i2 = (int)(__brev((unsigned)((512 - f) & 511)) >> 23);
            const float2 z1 = Zs[cc][i1];
            const float2 z2 = Zs[cc][i2];
            float re, im;
            if (part == 0) { re = 0.5f * (z1.x + z2.x); im = 0.5f * (z1.y - z2.y); }
            else           { re = 0.5f * (z1.y + z2.y); im = 0.5f * (z2.x - z1.x); }
            const float a = re * re + im * im;
            if (a > t3) {
                if (a > t0)      { t3 = t2; t2 = t1; t1 = t0; t0 = a; }
                else if (a > t1) { t3 = t2; t2 = t1; t1 = a; }
                else if (a > t2) { t3 = t2; t2 = a; }
                else               t3 = a;
            }
        }
        red4[rc][fi] = make_float4(t0, t1, t2, t3);
        __syncthreads();
        if (tid < 16) {
            float m0 = -1.f, m1 = -1.f, m2 = -1.f, m3 = -1.f;
            for (int q2 = 0; q2 < 16; ++q2) {
                const float4 c4 = red4[tid][q2];
                const float vals[4] = {c4.x, c4.y, c4.z, c4.w};
#pragma unroll
                for (int q = 0; q < 4; ++q) {
                    const float a = vals[q];
                    if (a > m3) {
                        if (a > m0)      { m3 = m2; m2 = m1; m1 = m0; m0 = a; }
                        else if (a > m1) { m3 = m2; m2 = m1; m1 = a; }
                        else if (a > m2) { m3 = m2; m2 = a; }
                        else               m3 = a;
                    }
                }
            }
            thr2[tid] = m3;
        }
        __syncthreads();

        // masked write (recompute unpack identically)
        const float th = thr2[rc];
        float* outp = dst + ((size_t)b * (257 * 512) + (size_t)dt * 16 + rc) * 2;
        for (int f = fi; f <= 256; f += 16) {
            const int i1 = (int)(__brev((unsigned)f) >> 23);
            const int i2 = (int)(__brev((unsigned)((512 - f) & 511)) >> 23);
            const float2 z1 = Zs[cc][i1];
            const float2 z2 = Zs[cc][i2];
            float re, im;
            if (part == 0) { re = 0.5f * (z1.x + z2.x); im = 0.5f * (z1.y - z2.y); }
            else           { re = 0.5f * (z1.y + z2.y); im = 0.5f * (z2.x - z1.x); }
            const float a = re * re + im * im;
            const float2 o = (a >= th) ? make_float2(re, im) : make_float2(0.f, 0.f);
            *reinterpret_cast<float2*>(outp + (size_t)f * 1024) = o;
        }
    }
}

// ---------------------------------------------------------------------------
// K3: per (b,f) row over d=512: att = qf*conj(kf); dual softmax; ctx = sm*vf.
// ---------------------------------------------------------------------------
__global__ __launch_bounds__(256) void att_softmax_ctx(
    const float* __restrict__ qf,
    const float* __restrict__ kf,
    float* __restrict__ vf)
{
    const int blk = blockIdx.x;
    const int b = blk / 257;
    const int f = blk % 257;
    const size_t row = ((size_t)b * 257 + f) * 512 * 2;
    const int tid = threadIdx.x;

    __shared__ float sred[20];

    const float4 q2 = *reinterpret_cast<const float4*>(qf + row + tid * 4);
    const float4 k2 = *reinterpret_cast<const float4*>(kf + row + tid * 4);
    const float4 v2 = *reinterpret_cast<const float4*>(vf + row + tid * 4);

    const float re0 = q2.x * k2.x + q2.y * k2.y;
    const float im0 = q2.y * k2.x - q2.x * k2.y;
    const float re1 = q2.z * k2.z + q2.w * k2.w;
    const float im1 = q2.w * k2.z - q2.z * k2.w;

    float mr = fmaxf(re0, re1), mi = fmaxf(im0, im1);
#pragma unroll
    for (int o = 32; o; o >>= 1) {
        mr = fmaxf(mr, __shfl_down(mr, o, 64));
        mi = fmaxf(mi, __shfl_down(mi, o, 64));
    }
    const int wid = tid >> 6, lane = tid & 63;
    if (lane == 0) { sred[wid] = mr; sred[4 + wid] = mi; }
    __syncthreads();
    if (tid == 0) {
        sred[16] = fmaxf(fmaxf(sred[0], sred[1]), fmaxf(sred[2], sred[3]));
        sred[17] = fmaxf(fmaxf(sred[4], sred[5]), fmaxf(sred[6], sred[7]));
    }
    __syncthreads();
    const float Mr = sred[16], Mi = sred[17];

    const float er0 = expf(re0 - Mr), er1 = expf(re1 - Mr);
    const float ei0 = expf(im0 - Mi), ei1 = expf(im1 - Mi);
    float sr = er0 + er1, si = ei0 + ei1;
#pragma unroll
    for (int o = 32; o; o >>= 1) {
        sr += __shfl_down(sr, o, 64);
        si += __shfl_down(si, o, 64);
    }
    if (lane == 0) { sred[8 + wid] = sr; sred[12 + wid] = si; }
    __syncthreads();
    if (tid == 0) {
        sred[18] = (sred[8] + sred[9]) + (sred[10] + sred[11]);
        sred[19] = (sred[12] + sred[13]) + (sred[14] + sred[15]);
    }
    __syncthreads();
    const float iSr = 1.0f / sred[18];
    const float iSi = 1.0f / sred[19];

    const float ar0 = er0 * iSr, ai0 = ei0 * iSi;
    const float ar1 = er1 * iSr, ai1 = ei1 * iSi;
    float4 o;
    o.x = ar0 * v2.x - ai0 * v2.y;
    o.y = ar0 * v2.y + ai0 * v2.x;
    o.z = ar1 * v2.z - ai1 * v2.w;
    o.w = ar1 * v2.w + ai1 * v2.z;
    *reinterpret_cast<float4*>(vf + row + tid * 4) = o;
}

// ---------------------------------------------------------------------------
// K4: sparse inverse rDFT along f per (b,d) column + residual add.
// ---------------------------------------------------------------------------
__global__ __launch_bounds__(256) void irfft_residual(
    const float* __restrict__ ctx,    // [B][257][512] float2
    const float* __restrict__ query,  // [B][512][512]
    float* __restrict__ x)            // [B][512][512]
{
    const int b  = blockIdx.x >> 5;
    const int dt = blockIdx.x & 31;
    const int tid = threadIdx.x;

    __shared__ float2 Cs[16][259];
    __shared__ float2 Tt[512];        // (cos, sin)(2*pi*j/512)

    for (int j = tid; j < 512; j += 256) {
        float sn, cs;
        sincosf(PI_F * (float)j * (1.0f / 256.0f), &sn, &cs);
        Tt[j] = make_float2(cs, sn);
    }
    {
        const int col = tid & 15;
        const int fr  = tid >> 4;
        const float* src = ctx + ((size_t)b * (257 * 512) + (size_t)dt * 16) * 2;
        for (int f = fr; f <= 256; f += 16) {
            Cs[col][f] = *reinterpret_cast<const float2*>(src + ((size_t)f * 512 + col) * 2);
        }
    }
    __syncthreads();

    const int col = tid & 15;
    const int w   = tid >> 4;
    float acc[32];
#pragma unroll
    for (int i = 0; i < 32; ++i) acc[i] = 0.f;

    for (int f = 0; f <= 256; ++f) {
        const float2 cv = Cs[col][f];
        if (cv.x != 0.f || cv.y != 0.f) {
            const float wgt = (f == 0 || f == 256) ? 1.f : 2.f;
            const float cr = cv.x * wgt, ci = cv.y * wgt;
            int idx = (f * w) & 511;
            const int stp = (f << 4) & 511;
#pragma unroll
            for (int i = 0; i < 32; ++i) {
                const float2 tw = Tt[idx];
                acc[i] = fmaf(cr, tw.x, fmaf(-ci, tw.y, acc[i]));
                idx = (idx + stp) & 511;
            }
        }
    }

    const float* qcol = query + (size_t)b * (512 * 512) + dt * 16 + col;
    float* xcol = x + (size_t)b * (512 * 512) + dt * 16 + col;
#pragma unroll
    for (int i = 0; i < 32; ++i) {
        const int l = w + (i << 4);
        xcol[(size_t)l * 512] = acc[i] * (1.0f / 512.0f) + qcol[(size_t)l * 512];
    }
}

// ---------------------------------------------------------------------------
// K5: LayerNorm along d.
// ---------------------------------------------------------------------------
__global__ __launch_bounds__(256) void layernorm_out(
    const float* __restrict__ x,
    const float* __restrict__ gamma,
    const float* __restrict__ beta,
    float* __restrict__ out)
{
    const int row = blockIdx.x;
    const float* xr = x + (size_t)row * 512;
    const int tid = threadIdx.x;
    __shared__ float sred[10];

    const float2 v = *reinterpret_cast<const float2*>(xr + tid * 2);
    float s = v.x + v.y;
    float q = v.x * v.x + v.y * v.y;
#pragma unroll
    for (int o = 32; o; o >>= 1) {
        s += __shfl_down(s, o, 64);
        q += __shfl_down(q, o, 64);
    }
    const int wid = tid >> 6, lane = tid & 63;
    if (lane == 0) { sred[wid] = s; sred[4 + wid] = q; }
    __syncthreads();
    if (tid == 0) {
        sred[8] = (sred[0] + sred[1]) + (sred[2] + sred[3]);
        sred[9] = (sred[4] + sred[5]) + (sred[6] + sred[7]);
    }
    __syncthreads();
    const float mean = sred[8] * (1.0f / 512.0f);
    const float var  = sred[9] * (1.0f / 512.0f) - mean * mean;
    const float rstd = 1.0f / sqrtf(var + 1e-5f);
    const float2 g  = *reinterpret_cast<const float2*>(gamma + tid * 2);
    const float2 be = *reinterpret_cast<const float2*>(beta + tid * 2);
    float2 o;
    o.x = (v.x - mean) * rstd * g.x + be.x;
    o.y = (v.y - mean) * rstd * g.y + be.y;
    *reinterpret_cast<float2*>(out + (size_t)row * 512 + tid * 2) = o;
}

// ---------------------------------------------------------------------------
extern "C" void kernel_launch(void* const* d_in, const int* in_sizes, int n_in,
                              void* d_out, int out_size, void* d_ws, size_t ws_size,
                              hipStream_t stream)
{
    const float* key   = (const float*)d_in[0];
    const float* value = (const float*)d_in[1];
    const float* query = (const float*)d_in[2];
    const float* Wk    = (const float*)d_in[3];
    const float* bk    = (const float*)d_in[4];
    const float* Wv    = (const float*)d_in[5];
    const float* bv    = (const float*)d_in[6];
    const float* Wq    = (const float*)d_in[7];
    const float* bq    = (const float*)d_in[8];
    const float* gamma = (const float*)d_in[9];
    const float* beta  = (const float*)d_in[10];
    float* out = (float*)d_out;

    float* ws = (float*)d_ws;
    float* tdom = ws;
    float* freq = ws + 8388608;
    const size_t FQ = 8421376;   // 32*257*512*2

    const float* Xs[3] = {key, value, query};
    const float* Wm[3] = {Wk, Wv, Wq};
    const float* Bs[3] = {bk, bv, bq};
    for (int t = 0; t < 3; ++t) {
        gemm_nt_bias<<<dim3(4, 256), 256, 0, stream>>>(Xs[t], Wm[t], Bs[t], tdom);
        fft_topk_mask<<<1024, 256, 0, stream>>>(tdom, freq + (size_t)t * FQ);
    }
    float* kfp = freq;
    float* vfp = freq + FQ;
    float* qfp = freq + 2 * FQ;

    att_softmax_ctx<<<32 * 257, 256, 0, stream>>>(qfp, kfp, vfp);
    irfft_residual<<<1024, 256, 0, stream>>>(vfp, query, tdom);
    layernorm_out<<<16384, 256, 0, stream>>>(tdom, gamma, beta, out);
}

// Round 10
// 604.596 us; speedup vs baseline: 6.9968x; 1.3869x over previous
//
#include <hip/hip_runtime.h>
#include <math.h>

#define PI_F 3.14159265358979323846f

static __device__ __forceinline__ float2 cmulf2(float2 a, float2 b) {
    return make_float2(a.x * b.x - a.y * b.y, a.x * b.y + a.y * b.x);
}

// ---------------------------------------------------------------------------
// K1: three GEMMs C_t = X_t @ W_t^T + b_t fused into one dispatch via
// blockIdx.z. Inner structure = round-4 static single-buffered 128x128x16
// (measured 124 us, VGPR 72): reg-staged dbuf variants all regressed
// (173/184 us, rounds 6/9) — hipcc defeats source pipelining. The lever here
// is occupancy: grid (4,128,3)=1536 blocks = 6 blocks/CU co-resident
// (VGPR 72 allows 7), so barrier drain of one block hides under others.
// ---------------------------------------------------------------------------
__global__ __launch_bounds__(256) void gemm3_nt_bias(
    const float* __restrict__ X0, const float* __restrict__ X1, const float* __restrict__ X2,
    const float* __restrict__ W0, const float* __restrict__ W1, const float* __restrict__ W2,
    const float* __restrict__ B0, const float* __restrict__ B1, const float* __restrict__ B2,
    float* __restrict__ O0, float* __restrict__ O1, float* __restrict__ O2)
{
    const float* A; const float* W; const float* bias; float* C;
    switch (blockIdx.z) {
        case 0:  A = X0; W = W0; bias = B0; C = O0; break;
        case 1:  A = X1; W = W1; bias = B1; C = O1; break;
        default: A = X2; W = W2; bias = B2; C = O2; break;
    }

    __shared__ float As[16][132];   // [k][m]
    __shared__ float Bs[16][132];   // [k][n]

    const int tid = threadIdx.x;
    const int m0 = blockIdx.y * 128;
    const int n0 = blockIdx.x * 128;
    const int tx = tid & 15;
    const int ty = tid >> 4;
    const int lr = tid >> 2;
    const int lc = (tid & 3) << 2;

    float acc[8][8];
#pragma unroll
    for (int i = 0; i < 8; ++i)
#pragma unroll
        for (int j = 0; j < 8; ++j) acc[i][j] = 0.f;

    for (int k0 = 0; k0 < 512; k0 += 16) {
#pragma unroll
        for (int it = 0; it < 2; ++it) {
            const int r = lr + (it << 6);
            const float4 av = *reinterpret_cast<const float4*>(
                A + (size_t)(m0 + r) * 512 + k0 + lc);
            As[lc + 0][r] = av.x; As[lc + 1][r] = av.y;
            As[lc + 2][r] = av.z; As[lc + 3][r] = av.w;
            const float4 wv = *reinterpret_cast<const float4*>(
                W + (size_t)(n0 + r) * 512 + k0 + lc);
            Bs[lc + 0][r] = wv.x; Bs[lc + 1][r] = wv.y;
            Bs[lc + 2][r] = wv.z; Bs[lc + 3][r] = wv.w;
        }
        __syncthreads();
#pragma unroll
        for (int kk = 0; kk < 16; ++kk) {
            const float4 a0 = *reinterpret_cast<const float4*>(&As[kk][ty << 3]);
            const float4 a1 = *reinterpret_cast<const float4*>(&As[kk][(ty << 3) + 4]);
            const float4 b0 = *reinterpret_cast<const float4*>(&Bs[kk][tx << 2]);
            const float4 b1 = *reinterpret_cast<const float4*>(&Bs[kk][64 + (tx << 2)]);
            const float a[8] = {a0.x, a0.y, a0.z, a0.w, a1.x, a1.y, a1.z, a1.w};
            const float b[8] = {b0.x, b0.y, b0.z, b0.w, b1.x, b1.y, b1.z, b1.w};
#pragma unroll
            for (int i = 0; i < 8; ++i)
#pragma unroll
                for (int j = 0; j < 8; ++j)
                    acc[i][j] = fmaf(a[i], b[j], acc[i][j]);
        }
        __syncthreads();
    }

    const float4 bv0 = *reinterpret_cast<const float4*>(bias + n0 + (tx << 2));
    const float4 bv1 = *reinterpret_cast<const float4*>(bias + n0 + 64 + (tx << 2));
#pragma unroll
    for (int i = 0; i < 8; ++i) {
        const int r = m0 + (ty << 3) + i;
        float4 o0, o1;
        o0.x = acc[i][0] + bv0.x; o0.y = acc[i][1] + bv0.y;
        o0.z = acc[i][2] + bv0.z; o0.w = acc[i][3] + bv0.w;
        o1.x = acc[i][4] + bv1.x; o1.y = acc[i][5] + bv1.y;
        o1.z = acc[i][6] + bv1.z; o1.w = acc[i][7] + bv1.w;
        *reinterpret_cast<float4*>(C + (size_t)r * 512 + n0 + (tx << 2)) = o0;
        *reinterpret_cast<float4*>(C + (size_t)r * 512 + n0 + 64 + (tx << 2)) = o1;
    }
}

// ---------------------------------------------------------------------------
// K2: rfft-512 along L + top-4 mask for up to 3 tensors (blockIdx.y selects).
// Packed-real: 16 real cols -> 8 complex FFT-512, radix-8-grouped DIF
// (3 LDS round trips), conjugate-symmetry unpack, per-col top-4 threshold,
// masked write. dst layout: [b][f][d] float2.
// ---------------------------------------------------------------------------
__global__ __launch_bounds__(256) void fft3_topk_mask(
    const float* __restrict__ S0, const float* __restrict__ S1, const float* __restrict__ S2,
    float* __restrict__ D0, float* __restrict__ D1, float* __restrict__ D2)
{
    const float* src; float* dst;
    switch (blockIdx.y) {
        case 0:  src = S0; dst = D0; break;
        case 1:  src = S1; dst = D1; break;
        default: src = S2; dst = D2; break;
    }

    const int b  = blockIdx.x >> 5;
    const int dt = blockIdx.x & 31;
    const int tid = threadIdx.x;

    __shared__ float2 Zs[8][522];
    __shared__ float2 TW[256];
    __shared__ float4 red4[16][16];
    __shared__ float  thr2[16];

    {
        float sn, cs;
        sincosf(-PI_F * (float)tid * (1.0f / 256.0f), &sn, &cs);
        TW[tid] = make_float2(cs, sn);
    }

    {
        const int c  = tid & 7;
        const int l0 = tid >> 3;
        const float* p = src + (size_t)b * 262144 + dt * 16 + 2 * c;
#pragma unroll
        for (int it = 0; it < 16; ++it) {
            const int l = l0 + (it << 5);
            Zs[c][l] = *reinterpret_cast<const float2*>(p + (size_t)l * 512);
        }
    }
    __syncthreads();

#define BF(aa, bb, tt) { \
        const float2 s_ = make_float2(aa.x + bb.x, aa.y + bb.y); \
        const float2 d_ = make_float2(aa.x - bb.x, aa.y - bb.y); \
        aa = s_; bb = cmulf2(d_, tt); }

    {
        const int c  = tid & 7;
        const int g0 = tid >> 3;
#pragma unroll
        for (int grp = 0; grp < 3; ++grp) {
            const int s  = grp * 3;
            const int lg = 6 - s;
            const int bs = 512 >> s;
#pragma unroll
            for (int h = 0; h < 2; ++h) {
                const int g   = g0 + (h << 5);
                const int j   = g & ((1 << lg) - 1);
                const int blk = g >> lg;
                const int base = blk * bs + j;
                const int J   = j << s;

                float2 x0 = Zs[c][base];
                float2 x1 = Zs[c][base + (1 << lg)];
                float2 x2 = Zs[c][base + (2 << lg)];
                float2 x3 = Zs[c][base + (3 << lg)];
                float2 x4 = Zs[c][base + (4 << lg)];
                float2 x5 = Zs[c][base + (5 << lg)];
                float2 x6 = Zs[c][base + (6 << lg)];
                float2 x7 = Zs[c][base + (7 << lg)];

                const float2 tA0 = TW[J];
                const float2 tA1 = TW[J + 64];
                const float2 tA2 = TW[J + 128];
                const float2 tA3 = TW[J + 192];
                BF(x0, x4, tA0); BF(x1, x5, tA1);
                BF(x2, x6, tA2); BF(x3, x7, tA3);

                const float2 tB0 = TW[2 * J];
                const float2 tB1 = TW[2 * J + 128];
                BF(x0, x2, tB0); BF(x1, x3, tB1);
                BF(x4, x6, tB0); BF(x5, x7, tB1);

                const float2 tC = TW[4 * J];
                BF(x0, x1, tC); BF(x2, x3, tC);
                BF(x4, x5, tC); BF(x6, x7, tC);

                Zs[c][base]             = x0;
                Zs[c][base + (1 << lg)] = x1;
                Zs[c][base + (2 << lg)] = x2;
                Zs[c][base + (3 << lg)] = x3;
                Zs[c][base + (4 << lg)] = x4;
                Zs[c][base + (5 << lg)] = x5;
                Zs[c][base + (6 << lg)] = x6;
                Zs[c][base + (7 << lg)] = x7;
            }
            __syncthreads();
        }
    }
#undef BF

    {
        const int rc = tid & 15;
        const int fi = tid >> 4;
        const int cc = rc >> 1;
        const int part = rc & 1;
        float t0 = -1.f, t1 = -1.f, t2 = -1.f, t3 = -1.f;
        for (int f = fi; f <= 256; f += 16) {
            const int i1 = (int)(__brev((unsigned)f) >> 23);
            const int i2 = (int)(__brev((unsigned)((512 - f) & 511)) >> 23);
            const float2 z1 = Zs[cc][i1];
            const float2 z2 = Zs[cc][i2];
            float re, im;
            if (part == 0) { re = 0.5f * (z1.x + z2.x); im = 0.5f * (z1.y - z2.y); }
            else           { re = 0.5f * (z1.y + z2.y); im = 0.5f * (z2.x - z1.x); }
            const float a = re * re + im * im;
            if (a > t3) {
                if (a > t0)      { t3 = t2; t2 = t1; t1 = t0; t0 = a; }
                else if (a > t1) { t3 = t2; t2 = t1; t1 = a; }
                else if (a > t2) { t3 = t2; t2 = a; }
                else               t3 = a;
            }
        }
        red4[rc][fi] = make_float4(t0, t1, t2, t3);
        __syncthreads();
        if (tid < 16) {
            float m0 = -1.f, m1 = -1.f, m2 = -1.f, m3 = -1.f;
            for (int q2 = 0; q2 < 16; ++q2) {
                const float4 c4 = red4[tid][q2];
                const float vals[4] = {c4.x, c4.y, c4.z, c4.w};
#pragma unroll
                for (int q = 0; q < 4; ++q) {
                    const float a = vals[q];
                    if (a > m3) {
                        if (a > m0)      { m3 = m2; m2 = m1; m1 = m0; m0 = a; }
                        else if (a > m1) { m3 = m2; m2 = m1; m1 = a; }
                        else if (a > m2) { m3 = m2; m2 = a; }
                        else               m3 = a;
                    }
                }
            }
            thr2[tid] = m3;
        }
        __syncthreads();

        const float th = thr2[rc];
        float* outp = dst + ((size_t)b * (257 * 512) + (size_t)dt * 16 + rc) * 2;
        for (int f = fi; f <= 256; f += 16) {
            const int i1 = (int)(__brev((unsigned)f) >> 23);
            const int i2 = (int)(__brev((unsigned)((512 - f) & 511)) >> 23);
            const float2 z1 = Zs[cc][i1];
            const float2 z2 = Zs[cc][i2];
            float re, im;
            if (part == 0) { re = 0.5f * (z1.x + z2.x); im = 0.5f * (z1.y - z2.y); }
            else           { re = 0.5f * (z1.y + z2.y); im = 0.5f * (z2.x - z1.x); }
            const float a = re * re + im * im;
            const float2 o = (a >= th) ? make_float2(re, im) : make_float2(0.f, 0.f);
            *reinterpret_cast<float2*>(outp + (size_t)f * 1024) = o;
        }
    }
}

// ---------------------------------------------------------------------------
// K3: per (b,f) row over d=512: att = qf*conj(kf); dual softmax; ctx = sm*vf.
// ---------------------------------------------------------------------------
__global__ __launch_bounds__(256) void att_softmax_ctx(
    const float* __restrict__ qf,
    const float* __restrict__ kf,
    float* __restrict__ vf)
{
    const int blk = blockIdx.x;
    const int b = blk / 257;
    const int f = blk % 257;
    const size_t row = ((size_t)b * 257 + f) * 512 * 2;
    const int tid = threadIdx.x;

    __shared__ float sred[20];

    const float4 q2 = *reinterpret_cast<const float4*>(qf + row + tid * 4);
    const float4 k2 = *reinterpret_cast<const float4*>(kf + row + tid * 4);
    const float4 v2 = *reinterpret_cast<const float4*>(vf + row + tid * 4);

    const float re0 = q2.x * k2.x + q2.y * k2.y;
    const float im0 = q2.y * k2.x - q2.x * k2.y;
    const float re1 = q2.z * k2.z + q2.w * k2.w;
    const float im1 = q2.w * k2.z - q2.z * k2.w;

    float mr = fmaxf(re0, re1), mi = fmaxf(im0, im1);
#pragma unroll
    for (int o = 32; o; o >>= 1) {
        mr = fmaxf(mr, __shfl_down(mr, o, 64));
        mi = fmaxf(mi, __shfl_down(mi, o, 64));
    }
    const int wid = tid >> 6, lane = tid & 63;
    if (lane == 0) { sred[wid] = mr; sred[4 + wid] = mi; }
    __syncthreads();
    if (tid == 0) {
        sred[16] = fmaxf(fmaxf(sred[0], sred[1]), fmaxf(sred[2], sred[3]));
        sred[17] = fmaxf(fmaxf(sred[4], sred[5]), fmaxf(sred[6], sred[7]));
    }
    __syncthreads();
    const float Mr = sred[16], Mi = sred[17];

    const float er0 = expf(re0 - Mr), er1 = expf(re1 - Mr);
    const float ei0 = expf(im0 - Mi), ei1 = expf(im1 - Mi);
    float sr = er0 + er1, si = ei0 + ei1;
#pragma unroll
    for (int o = 32; o; o >>= 1) {
        sr += __shfl_down(sr, o, 64);
        si += __shfl_down(si, o, 64);
    }
    if (lane == 0) { sred[8 + wid] = sr; sred[12 + wid] = si; }
    __syncthreads();
    if (tid == 0) {
        sred[18] = (sred[8] + sred[9]) + (sred[10] + sred[11]);
        sred[19] = (sred[12] + sred[13]) + (sred[14] + sred[15]);
    }
    __syncthreads();
    const float iSr = 1.0f / sred[18];
    const float iSi = 1.0f / sred[19];

    const float ar0 = er0 * iSr, ai0 = ei0 * iSi;
    const float ar1 = er1 * iSr, ai1 = ei1 * iSi;
    float4 o;
    o.x = ar0 * v2.x - ai0 * v2.y;
    o.y = ar0 * v2.y + ai0 * v2.x;
    o.z = ar1 * v2.z - ai1 * v2.w;
    o.w = ar1 * v2.w + ai1 * v2.z;
    *reinterpret_cast<float4*>(vf + row + tid * 4) = o;
}

// ---------------------------------------------------------------------------
// K4: sparse inverse rDFT along f per (b,d) column + residual add.
// ---------------------------------------------------------------------------
__global__ __launch_bounds__(256) void irfft_residual(
    const float* __restrict__ ctx,    // [B][257][512] float2
    const float* __restrict__ query,  // [B][512][512]
    float* __restrict__ x)            // [B][512][512]
{
    const int b  = blockIdx.x >> 5;
    const int dt = blockIdx.x & 31;
    const int tid = threadIdx.x;

    __shared__ float2 Cs[16][259];
    __shared__ float2 Tt[512];

    for (int j = tid; j < 512; j += 256) {
        float sn, cs;
        sincosf(PI_F * (float)j * (1.0f / 256.0f), &sn, &cs);
        Tt[j] = make_float2(cs, sn);
    }
    {
        const int col = tid & 15;
        const int fr  = tid >> 4;
        const float* src = ctx + ((size_t)b * (257 * 512) + (size_t)dt * 16) * 2;
        for (int f = fr; f <= 256; f += 16) {
            Cs[col][f] = *reinterpret_cast<const float2*>(src + ((size_t)f * 512 + col) * 2);
        }
    }
    __syncthreads();

    const int col = tid & 15;
    const int w   = tid >> 4;
    float acc[32];
#pragma unroll
    for (int i = 0; i < 32; ++i) acc[i] = 0.f;

    for (int f = 0; f <= 256; ++f) {
        const float2 cv = Cs[col][f];
        if (cv.x != 0.f || cv.y != 0.f) {
            const float wgt = (f == 0 || f == 256) ? 1.f : 2.f;
            const float cr = cv.x * wgt, ci = cv.y * wgt;
            int idx = (f * w) & 511;
            const int stp = (f << 4) & 511;
#pragma unroll
            for (int i = 0; i < 32; ++i) {
                const float2 tw = Tt[idx];
                acc[i] = fmaf(cr, tw.x, fmaf(-ci, tw.y, acc[i]));
                idx = (idx + stp) & 511;
            }
        }
    }

    const float* qcol = query + (size_t)b * (512 * 512) + dt * 16 + col;
    float* xcol = x + (size_t)b * (512 * 512) + dt * 16 + col;
#pragma unroll
    for (int i = 0; i < 32; ++i) {
        const int l = w + (i << 4);
        xcol[(size_t)l * 512] = acc[i] * (1.0f / 512.0f) + qcol[(size_t)l * 512];
    }
}

// ---------------------------------------------------------------------------
// K5: LayerNorm along d.
// ---------------------------------------------------------------------------
__global__ __launch_bounds__(256) void layernorm_out(
    const float* __restrict__ x,
    const float* __restrict__ gamma,
    const float* __restrict__ beta,
    float* __restrict__ out)
{
    const int row = blockIdx.x;
    const float* xr = x + (size_t)row * 512;
    const int tid = threadIdx.x;
    __shared__ float sred[10];

    const float2 v = *reinterpret_cast<const float2*>(xr + tid * 2);
    float s = v.x + v.y;
    float q = v.x * v.x + v.y * v.y;
#pragma unroll
    for (int o = 32; o; o >>= 1) {
        s += __shfl_down(s, o, 64);
        q += __shfl_down(q, o, 64);
    }
    const int wid = tid >> 6, lane = tid & 63;
    if (lane == 0) { sred[wid] = s; sred[4 + wid] = q; }
    __syncthreads();
    if (tid == 0) {
        sred[8] = (sred[0] + sred[1]) + (sred[2] + sred[3]);
        sred[9] = (sred[4] + sred[5]) + (sred[6] + sred[7]);
    }
    __syncthreads();
    const float mean = sred[8] * (1.0f / 512.0f);
    const float var  = sred[9] * (1.0f / 512.0f) - mean * mean;
    const float rstd = 1.0f / sqrtf(var + 1e-5f);
    const float2 g  = *reinterpret_cast<const float2*>(gamma + tid * 2);
    const float2 be = *reinterpret_cast<const float2*>(beta + tid * 2);
    float2 o;
    o.x = (v.x - mean) * rstd * g.x + be.x;
    o.y = (v.y - mean) * rstd * g.y + be.y;
    *reinterpret_cast<float2*>(out + (size_t)row * 512 + tid * 2) = o;
}

// ---------------------------------------------------------------------------
extern "C" void kernel_launch(void* const* d_in, const int* in_sizes, int n_in,
                              void* d_out, int out_size, void* d_ws, size_t ws_size,
                              hipStream_t stream)
{
    const float* key   = (const float*)d_in[0];
    const float* value = (const float*)d_in[1];
    const float* query = (const float*)d_in[2];
    const float* Wk    = (const float*)d_in[3];
    const float* bk    = (const float*)d_in[4];
    const float* Wv    = (const float*)d_in[5];
    const float* bv    = (const float*)d_in[6];
    const float* Wq    = (const float*)d_in[7];
    const float* bq    = (const float*)d_in[8];
    const float* gamma = (const float*)d_in[9];
    const float* beta  = (const float*)d_in[10];
    float* out = (float*)d_out;

    float* ws = (float*)d_ws;
    const size_t TD = 8388608;   // 32*512*512 floats
    const size_t FQ = 8421376;   // 32*257*512*2 floats
    // Concurrent path needs 3*TD + 3*FQ floats = ~201.7 MB.
    const size_t NEED_BYTES = (3 * TD + 3 * FQ) * sizeof(float);

    if (ws_size >= NEED_BYTES) {
        // --- concurrent path: 1 fused GEMM dispatch + 1 fused FFT dispatch ---
        float* t0 = ws;                 // key  time-domain
        float* t1 = ws + TD;            // value
        float* t2 = ws + 2 * TD;        // query
        float* f0 = ws + 3 * TD;        // kf
        float* f1 = f0 + FQ;            // vf (becomes ctx in-place)
        float* f2 = f1 + FQ;            // qf

        gemm3_nt_bias<<<dim3(4, 128, 3), 256, 0, stream>>>(
            key, value, query, Wk, Wv, Wq, bk, bv, bq, t0, t1, t2);
        fft3_topk_mask<<<dim3(1024, 3), 256, 0, stream>>>(
            t0, t1, t2, f0, f1, f2);

        att_softmax_ctx<<<32 * 257, 256, 0, stream>>>(f2, f0, f1);
        irfft_residual<<<1024, 256, 0, stream>>>(f1, query, t0);
        layernorm_out<<<16384, 256, 0, stream>>>(t0, gamma, beta, out);
    } else {
        // --- fallback: sequential per-tensor (round-4 layout) ---
        float* tdom = ws;
        float* freq = ws + TD;
        const float* Xs[3] = {key, value, query};
        const float* Wm[3] = {Wk, Wv, Wq};
        const float* Bs[3] = {bk, bv, bq};
        for (int t = 0; t < 3; ++t) {
            gemm3_nt_bias<<<dim3(4, 128, 1), 256, 0, stream>>>(
                Xs[t], Xs[t], Xs[t], Wm[t], Wm[t], Wm[t],
                Bs[t], Bs[t], Bs[t], tdom, tdom, tdom);
            fft3_topk_mask<<<dim3(1024, 1), 256, 0, stream>>>(
                tdom, tdom, tdom,
                freq + (size_t)t * FQ, freq + (size_t)t * FQ, freq + (size_t)t * FQ);
        }
        float* kfp = freq;
        float* vfp = freq + FQ;
        float* qfp = freq + 2 * FQ;
        att_softmax_ctx<<<32 * 257, 256, 0, stream>>>(qfp, kfp, vfp);
        irfft_residual<<<1024, 256, 0, stream>>>(vfp, query, tdom);
        layernorm_out<<<16384, 256, 0, stream>>>(tdom, gamma, beta, out);
    }
}